// Round 1
// baseline (334.246 us; speedup 1.0000x reference)
//
#include <hip/hip_runtime.h>
#include <hip/hip_bf16.h>
#include <math.h>

#define BB 4
#define HH 16
#define SS 1024
#define DD 64

typedef __attribute__((ext_vector_type(8))) short bf16x8;   // MFMA A/B frag (8 bf16)
typedef __attribute__((ext_vector_type(4))) float f32x4;    // MFMA C/D frag

static __device__ __forceinline__ short f2bf(float f) {
    unsigned u = __builtin_bit_cast(unsigned, f);
    u += 0x7fffu + ((u >> 16) & 1u);   // RNE
    return (short)(u >> 16);
}

static __device__ __forceinline__ bf16x8 load8_bf16(const float* p) {
    const float4* p4 = reinterpret_cast<const float4*>(p);
    float4 a = p4[0], b = p4[1];
    bf16x8 f;
    f[0]=f2bf(a.x); f[1]=f2bf(a.y); f[2]=f2bf(a.z); f[3]=f2bf(a.w);
    f[4]=f2bf(b.x); f[5]=f2bf(b.y); f[6]=f2bf(b.z); f[7]=f2bf(b.w);
    return f;
}

// One workgroup = (b, 16-row q-tile), 8 waves.
// Wave w: phase-1 computes per-head scores P_h for h in {2w,2w+1};
//         phase-2 mixes/softmaxes/PVs for output heads g in {2w,2w+1}.
__global__ __launch_bounds__(512) void hca_fused(
    const float* __restrict__ xq, const float* __restrict__ xk,
    const float* __restrict__ xv, const float* __restrict__ Wm,
    const int* __restrict__ causalp, float* __restrict__ out)
{
    // P[pos = q*64 + k][16 h] f32, quad-of-4 XOR swizzle on the h-quads.
    __shared__ float P[16384];   // 64 KB

    const int tid  = threadIdx.x;
    const int lane = tid & 63;
    const int w    = tid >> 6;     // wave 0..7
    const int l15  = lane & 15;
    const int lg   = lane >> 4;    // 0..3

    const int bid = blockIdx.x;
    const int b   = bid >> 6;
    const int qt  = bid & 63;
    const int q0  = qt << 4;

    const int causal = causalp[0];
    const int hA = w << 1;         // this wave's head/output-head pair base

    // W rows for g = hA, hA+1, with 1/sqrt(D)=0.125 folded in
    float wmix[2][16];
#pragma unroll
    for (int h = 0; h < 16; ++h) {
        wmix[0][h] = Wm[hA * 16 + h] * 0.125f;
        wmix[1][h] = Wm[(hA + 1) * 16 + h] * 0.125f;
    }

    // Q A-fragments for the 2 phase-1 heads (m = l15 = q row, kcontr = lg*8+i)
    bf16x8 qf[2][2];
#pragma unroll
    for (int hi = 0; hi < 2; ++hi) {
        const float* qp = xq + ((size_t)(b * HH + hA + hi) * SS + q0 + l15) * DD + lg * 8;
#pragma unroll
        for (int ds = 0; ds < 2; ++ds)
            qf[hi][ds] = load8_bf16(qp + ds * 32);
    }

    f32x4 oacc[2][4];
#pragma unroll
    for (int gi = 0; gi < 2; ++gi)
#pragma unroll
        for (int nt = 0; nt < 4; ++nt)
            oacc[gi][nt] = (f32x4){0.f, 0.f, 0.f, 0.f};
    float mrun[2] = {-INFINITY, -INFINITY};
    float lrun[2] = {0.f, 0.f};

    const int nk = (q0 + 16 + 63) >> 6;   // causal: k <= q0+15

    for (int kst = 0; kst < nk; ++kst) {
        const int k0 = kst << 6;

        // ---------- phase 1: P_h[16q x 64k] for h = hA, hA+1 ----------
        f32x4 pacc[2][4];
#pragma unroll
        for (int hi = 0; hi < 2; ++hi) {
            const float* kb = xk + ((size_t)(b * HH + hA + hi) * SS + k0) * DD;
#pragma unroll
            for (int kt = 0; kt < 4; ++kt) {
                f32x4 acc = (f32x4){0.f, 0.f, 0.f, 0.f};
#pragma unroll
                for (int ds = 0; ds < 2; ++ds) {
                    // B-frag: n = l15 -> k col (kt*16+l15), kcontr = lg*8+i -> d
                    bf16x8 kf = load8_bf16(kb + (size_t)(kt * 16 + l15) * DD + ds * 32 + lg * 8);
                    acc = __builtin_amdgcn_mfma_f32_16x16x32_bf16(qf[hi][ds], kf, acc, 0, 0, 0);
                }
                pacc[hi][kt] = acc;
            }
        }
        // write both heads' value at (q,k) as one b64 (h-pair is consecutive)
#pragma unroll
        for (int kt = 0; kt < 4; ++kt) {
#pragma unroll
            for (int r = 0; r < 4; ++r) {
                int q = lg * 4 + r;                 // C/D: row=(lane>>4)*4+reg
                int k = kt * 16 + l15;              //      col=lane&15
                int pos = q * 64 + k;
                int s = (pos & 3) ^ ((pos >> 8) & 3);
                int idx = pos * 16 + (((w >> 1) ^ s) << 2) + ((w & 1) << 1);
                float2 v; v.x = pacc[0][kt][r]; v.y = pacc[1][kt][r];
                *reinterpret_cast<float2*>(&P[idx]) = v;
            }
        }
        __syncthreads();

        // ---------- phase 2: mix + online softmax + PV for g = hA, hA+1 ----------
        // lane holds q = l15; k(j): j<8 -> lg*8+j, j>=8 -> 32+lg*8+(j-8)
        // (this is exactly the 16x16x32 A-frag contraction layout for PV)
        float sm[2][16];
#pragma unroll
        for (int j = 0; j < 16; ++j) {
            int k = (j < 8) ? (lg * 8 + j) : (32 + lg * 8 + (j - 8));
            int pos = l15 * 64 + k;
            int s = (pos & 3) ^ ((pos >> 8) & 3);
            float accA = 0.f, accB = 0.f;
#pragma unroll
            for (int quad = 0; quad < 4; ++quad) {
                int idx = pos * 16 + ((quad ^ s) << 2);
                const f32x4 v4 = *reinterpret_cast<const f32x4*>(&P[idx]);
#pragma unroll
                for (int e = 0; e < 4; ++e) {
                    accA = fmaf(wmix[0][quad * 4 + e], v4[e], accA);
                    accB = fmaf(wmix[1][quad * 4 + e], v4[e], accB);
                }
            }
            if (causal && (k0 + k > q0 + l15)) { accA = -INFINITY; accB = -INFINITY; }
            sm[0][j] = accA; sm[1][j] = accB;
        }

#pragma unroll
        for (int gi = 0; gi < 2; ++gi) {
            float mt = sm[gi][0];
#pragma unroll
            for (int j = 1; j < 16; ++j) mt = fmaxf(mt, sm[gi][j]);
            mt = fmaxf(mt, __shfl_xor(mt, 16));
            mt = fmaxf(mt, __shfl_xor(mt, 32));
            const float mnew = fmaxf(mrun[gi], mt);
            const float scl = __expf(mrun[gi] - mnew);  // first tile: exp(-inf)=0
            mrun[gi] = mnew;

            float ps = 0.f;
            bf16x8 pa[2];
#pragma unroll
            for (int j = 0; j < 16; ++j) {
                float p = __expf(sm[gi][j] - mnew);     // masked -> exp(-inf)=0
                ps += p;
                pa[j >> 3][j & 7] = f2bf(p);
            }
            lrun[gi] = lrun[gi] * scl + ps;

            // redistribute row rescale factor to C-layout rows q = lg*4+r
            int scli = __builtin_bit_cast(int, scl);
            float sclq[4];
#pragma unroll
            for (int r = 0; r < 4; ++r) {
                int v = __builtin_amdgcn_ds_bpermute((lg * 4 + r) * 4, scli);
                sclq[r] = __builtin_bit_cast(float, v);
            }
#pragma unroll
            for (int nt = 0; nt < 4; ++nt)
#pragma unroll
                for (int r = 0; r < 4; ++r) oacc[gi][nt][r] *= sclq[r];

            // PV: O[q,d] += Pr[q,k] V[k,d]; B-frag: n=l15 -> d, kcontr=lg*8+i -> k
            const float* vb = xv + ((size_t)(b * HH + hA + gi) * SS + k0) * DD;
#pragma unroll
            for (int kc = 0; kc < 2; ++kc) {
#pragma unroll
                for (int nt = 0; nt < 4; ++nt) {
                    bf16x8 vf;
#pragma unroll
                    for (int i = 0; i < 8; ++i) {
                        int k = kc * 32 + lg * 8 + i;
                        vf[i] = f2bf(vb[(size_t)k * DD + nt * 16 + l15]);
                    }
                    oacc[gi][nt] = __builtin_amdgcn_mfma_f32_16x16x32_bf16(pa[kc], vf, oacc[gi][nt], 0, 0, 0);
                }
            }
        }
        __syncthreads();
    }

    // ---------- epilogue: normalize by row sum, write [B,S,H,D] ----------
#pragma unroll
    for (int gi = 0; gi < 2; ++gi) {
        float lt = lrun[gi];
        lt += __shfl_xor(lt, 16);
        lt += __shfl_xor(lt, 32);
        int lti = __builtin_bit_cast(int, lt);
        float linv[4];
#pragma unroll
        for (int r = 0; r < 4; ++r) {
            int v = __builtin_amdgcn_ds_bpermute((lg * 4 + r) * 4, lti);
            linv[r] = 1.0f / __builtin_bit_cast(float, v);
        }
        const int g = hA + gi;
#pragma unroll
        for (int nt = 0; nt < 4; ++nt)
#pragma unroll
            for (int r = 0; r < 4; ++r) {
                int q = lg * 4 + r;
                out[((size_t)(b * SS + q0 + q) * HH + g) * DD + nt * 16 + l15] =
                    oacc[gi][nt][r] * linv[r];
            }
    }
}

extern "C" void kernel_launch(void* const* d_in, const int* in_sizes, int n_in,
                              void* d_out, int out_size, void* d_ws, size_t ws_size,
                              hipStream_t stream) {
    const float* xq = (const float*)d_in[0];
    const float* xk = (const float*)d_in[1];
    const float* xv = (const float*)d_in[2];
    const float* Wm = (const float*)d_in[3];
    const int* causal = (const int*)d_in[4];
    float* out = (float*)d_out;

    dim3 grid(BB * (SS / 16));   // 256 workgroups: (b, q-tile)
    dim3 block(512);             // 8 waves
    hca_fused<<<grid, block, 0, stream>>>(xq, xk, xv, Wm, causal, out);
}

// Round 2
// 187.899 us; speedup vs baseline: 1.7789x; 1.7789x over previous
//
#include <hip/hip_runtime.h>
#include <math.h>

#define NB 4
#define HH 16
#define SS 1024
#define DD 64

typedef __attribute__((ext_vector_type(8))) short bf16x8;
typedef __attribute__((ext_vector_type(4))) float f32x4;
typedef __attribute__((ext_vector_type(4))) int i32x4;

static __device__ __forceinline__ short f2bf(float f) {
    unsigned u = __builtin_bit_cast(unsigned, f);
    u += 0x7fffu + ((u >> 16) & 1u);   // RNE
    return (short)(u >> 16);
}
static __device__ __forceinline__ float bflo(int w) {
    return __builtin_bit_cast(float, (unsigned)w << 16);
}
static __device__ __forceinline__ float bfhi(int w) {
    return __builtin_bit_cast(float, (unsigned)w & 0xffff0000u);
}
// XOR-swizzle for P: 16B-unit index = (pos*2+u) ^ swzf(pos); spreads mix-read
// b128s over all 8 bank groups (lane bits lg0^l0, lg1^l1, l2) and writes over 8.
static __device__ __forceinline__ int swzf(int pos) {
    return (((pos >> 3) ^ (pos >> 6)) & 1) | ((((pos >> 4) ^ (pos >> 7)) & 1) << 1)
         | (((pos >> 8) & 1) << 2);
}

static __device__ __forceinline__ bf16x8 load8_bf16(const float* p) {
    const float4* p4 = reinterpret_cast<const float4*>(p);
    float4 a = p4[0], b = p4[1];
    bf16x8 f;
    f[0]=f2bf(a.x); f[1]=f2bf(a.y); f[2]=f2bf(a.z); f[3]=f2bf(a.w);
    f[4]=f2bf(b.x); f[5]=f2bf(b.y); f[6]=f2bf(b.z); f[7]=f2bf(b.w);
    return f;
}

// ---------- prep: f32 -> bf16 copy (for K) ----------
__global__ __launch_bounds__(256) void prep_bf16(const float* __restrict__ x,
                                                 short* __restrict__ y, int n8) {
    int i = blockIdx.x * 256 + threadIdx.x;
    if (i >= n8) return;
    const float4* p = reinterpret_cast<const float4*>(x) + (size_t)i * 2;
    float4 a = p[0], b = p[1];
    bf16x8 o;
    o[0]=f2bf(a.x); o[1]=f2bf(a.y); o[2]=f2bf(a.z); o[3]=f2bf(a.w);
    o[4]=f2bf(b.x); o[5]=f2bf(b.y); o[6]=f2bf(b.z); o[7]=f2bf(b.w);
    *(reinterpret_cast<bf16x8*>(y) + i) = o;
}

// ---------- prep: V [B,H,S,D] f32 -> V^T [B,H,D,S] bf16 ----------
__global__ __launch_bounds__(256) void prep_vT(const float* __restrict__ xv,
                                               short* __restrict__ vT) {
    __shared__ float T[64][65];
    int bid = blockIdx.x;            // (b*H+h)*16 + s-tile
    int bh = bid >> 4, st = bid & 15;
    const float* src = xv + ((size_t)bh * SS + st * 64) * DD;
    int t = threadIdx.x;
#pragma unroll
    for (int r = 0; r < 4; ++r) {
        int s = r * 16 + (t >> 4), d = (t & 15) * 4;
        float4 v = *reinterpret_cast<const float4*>(src + s * DD + d);
        T[s][d] = v.x; T[s][d+1] = v.y; T[s][d+2] = v.z; T[s][d+3] = v.w;
    }
    __syncthreads();
#pragma unroll
    for (int r = 0; r < 4; ++r) {
        int d = r * 16 + (t >> 4), s0 = (t & 15) * 4;
        ushort4 o;
        o.x = (ushort)f2bf(T[s0][d]);   o.y = (ushort)f2bf(T[s0+1][d]);
        o.z = (ushort)f2bf(T[s0+2][d]); o.w = (ushort)f2bf(T[s0+3][d]);
        *reinterpret_cast<ushort4*>(vT + ((size_t)bh * DD + d) * SS + st * 64 + s0) = o;
    }
}

// One block = (b, 16-row q-tile, head-half). 8 waves.
// Phase 1: wave w computes P for heads {2w,2w+1} (duplicated across the 2 halves).
// Phase 2: wave w mixes/softmaxes/PVs output head g = half*8+w.
__global__ __launch_bounds__(512, 4) void hca_fused(
    const float* __restrict__ xq, const short* __restrict__ kb,
    const short* __restrict__ vT, const float* __restrict__ Wm,
    const int* __restrict__ causalp, float* __restrict__ out)
{
    __shared__ i32x4 P[2][2048];   // double-buffered bf16 scores [pos=q*64+k][16h], swizzled

    const int tid  = threadIdx.x;
    const int lane = tid & 63;
    const int w    = tid >> 6;
    const int l15  = lane & 15;
    const int lg   = lane >> 4;

    // bid -> (qt, b, half): 16-bid chunks pair qt=63-g with qt=g (work-sum const),
    // long tiles dispatched first.
    const int bid   = blockIdx.x;
    const int g8    = bid >> 4;
    const int which = (bid >> 3) & 1;
    const int b     = (bid >> 1) & 3;
    const int half  = bid & 1;
    const int qt    = which ? g8 : 63 - g8;
    const int q0    = qt << 4;

    const int causal = causalp[0];
    const int g  = half * 8 + w;     // output head for phase 2
    const int hA = w << 1;           // phase-1 head pair

    float wmix[16];
#pragma unroll
    for (int h = 0; h < 16; ++h) wmix[h] = Wm[g * 16 + h] * 0.125f;

    // Q A-fragments (f32 source, once per block)
    bf16x8 qf[2][2];
#pragma unroll
    for (int hi = 0; hi < 2; ++hi) {
        const float* qp = xq + ((size_t)(b * HH + hA + hi) * SS + q0 + l15) * DD + lg * 8;
#pragma unroll
        for (int ds = 0; ds < 2; ++ds) qf[hi][ds] = load8_bf16(qp + ds * 32);
    }

    f32x4 oacc[4];
#pragma unroll
    for (int nt = 0; nt < 4; ++nt) oacc[nt] = (f32x4){0.f, 0.f, 0.f, 0.f};
    float mrun = -INFINITY, lrun = 0.f;

    // read-side swizzle bits are lane-constant for the phase-2 pattern
    const int fl = ((lg ^ l15) & 1) | ((((lg >> 1) ^ (l15 >> 1)) & 1) << 1)
                 | (((l15 >> 2) & 1) << 2);

    const int nk = causal ? ((q0 + 16 + 63) >> 6) : (SS >> 6);

    for (int kst = 0; kst < nk; ++kst) {
        const int k0  = kst << 6;
        const int buf = kst & 1;

        // ---------- phase 1: P_h[16q x 64k] for h = 2w, 2w+1 ----------
        f32x4 pacc[2][4];
#pragma unroll
        for (int hi = 0; hi < 2; ++hi) {
            const short* kbh = kb + ((size_t)(b * HH + hA + hi) * SS + k0) * DD;
#pragma unroll
            for (int kt = 0; kt < 4; ++kt) {
                f32x4 acc = (f32x4){0.f, 0.f, 0.f, 0.f};
#pragma unroll
                for (int ds = 0; ds < 2; ++ds) {
                    bf16x8 kf = *reinterpret_cast<const bf16x8*>(
                        kbh + (size_t)(kt * 16 + l15) * DD + ds * 32 + lg * 8);
                    acc = __builtin_amdgcn_mfma_f32_16x16x32_bf16(qf[hi][ds], kf, acc, 0, 0, 0);
                }
                pacc[hi][kt] = acc;
            }
        }
#pragma unroll
        for (int kt = 0; kt < 4; ++kt) {
#pragma unroll
            for (int r = 0; r < 4; ++r) {
                int q = lg * 4 + r, k = kt * 16 + l15;
                int pos = q * 64 + k;
                int su = ((pos << 1) + (w >> 2)) ^ swzf(pos);
                unsigned pk = (unsigned)(unsigned short)f2bf(pacc[0][kt][r])
                            | ((unsigned)(unsigned short)f2bf(pacc[1][kt][r]) << 16);
                reinterpret_cast<int*>(&P[buf][su])[w & 3] = (int)pk;
            }
        }
        __syncthreads();   // single barrier per step (double-buffered P)

        // ---------- phase 2: mix + online softmax + PV for head g ----------
        float sm[16];
#pragma unroll
        for (int j = 0; j < 16; ++j) {
            int kk  = (j < 8) ? (lg * 8 + j) : (32 + lg * 8 + (j - 8));
            int pos = l15 * 64 + kk;
            int su0 = (pos << 1) ^ fl;
            i32x4 r0 = P[buf][su0];
            i32x4 r1 = P[buf][su0 ^ 1];
            float a0 = 0.f, a1 = 0.f, a2 = 0.f, a3 = 0.f;
#pragma unroll
            for (int p2 = 0; p2 < 4; ++p2) {
                a0 = fmaf(wmix[2 * p2],     bflo(r0[p2]), a0);
                a1 = fmaf(wmix[2 * p2 + 1], bfhi(r0[p2]), a1);
                a2 = fmaf(wmix[8 + 2 * p2],     bflo(r1[p2]), a2);
                a3 = fmaf(wmix[8 + 2 * p2 + 1], bfhi(r1[p2]), a3);
            }
            float s = (a0 + a1) + (a2 + a3);
            if (causal && (k0 + kk > q0 + l15)) s = -INFINITY;
            sm[j] = s;
        }

        float mt = sm[0];
#pragma unroll
        for (int j = 1; j < 16; ++j) mt = fmaxf(mt, sm[j]);
        mt = fmaxf(mt, __shfl_xor(mt, 16));
        mt = fmaxf(mt, __shfl_xor(mt, 32));
        const float mnew = fmaxf(mrun, mt);
        const float scl  = __expf(mrun - mnew);
        mrun = mnew;

        float ps = 0.f;
        bf16x8 pa[2];
#pragma unroll
        for (int j = 0; j < 16; ++j) {
            float p = __expf(sm[j] - mnew);
            ps += p;
            pa[j >> 3][j & 7] = f2bf(p);
        }
        lrun = lrun * scl + ps;

        int scli = __builtin_bit_cast(int, scl);
        float sclq[4];
#pragma unroll
        for (int r = 0; r < 4; ++r) {
            int v = __builtin_amdgcn_ds_bpermute((lg * 4 + r) * 4, scli);
            sclq[r] = __builtin_bit_cast(float, v);
        }
#pragma unroll
        for (int nt = 0; nt < 4; ++nt)
#pragma unroll
            for (int r = 0; r < 4; ++r) oacc[nt][r] *= sclq[r];

        // PV from transposed bf16 V: one contiguous 16B load per fragment
        const short* vb = vT + (size_t)(b * HH + g) * DD * SS + k0;
#pragma unroll
        for (int kc = 0; kc < 2; ++kc) {
#pragma unroll
            for (int nt = 0; nt < 4; ++nt) {
                bf16x8 vf = *reinterpret_cast<const bf16x8*>(
                    vb + (size_t)(nt * 16 + l15) * SS + kc * 32 + lg * 8);
                oacc[nt] = __builtin_amdgcn_mfma_f32_16x16x32_bf16(pa[kc], vf, oacc[nt], 0, 0, 0);
            }
        }
        // no trailing barrier: next step writes the other P buffer; the barrier
        // after its writes guarantees this step's reads finished block-wide.
    }

    // ---------- epilogue ----------
    float lt = lrun;
    lt += __shfl_xor(lt, 16);
    lt += __shfl_xor(lt, 32);
    int lti = __builtin_bit_cast(int, lt);
    float linv[4];
#pragma unroll
    for (int r = 0; r < 4; ++r) {
        int v = __builtin_amdgcn_ds_bpermute((lg * 4 + r) * 4, lti);
        linv[r] = 1.0f / __builtin_bit_cast(float, v);
    }
#pragma unroll
    for (int nt = 0; nt < 4; ++nt)
#pragma unroll
        for (int r = 0; r < 4; ++r) {
            int q = lg * 4 + r;
            out[((size_t)(b * SS + q0 + q) * HH + g) * DD + nt * 16 + l15] =
                oacc[nt][r] * linv[r];
        }
}

extern "C" void kernel_launch(void* const* d_in, const int* in_sizes, int n_in,
                              void* d_out, int out_size, void* d_ws, size_t ws_size,
                              hipStream_t stream) {
    const float* xq = (const float*)d_in[0];
    const float* xk = (const float*)d_in[1];
    const float* xv = (const float*)d_in[2];
    const float* Wm = (const float*)d_in[3];
    const int* causal = (const int*)d_in[4];
    float* out = (float*)d_out;

    short* vT  = (short*)d_ws;                              // 8 MB bf16 V^T
    short* kbf = vT + (size_t)NB * HH * DD * SS;            // 8 MB bf16 K

    const int n8 = NB * HH * SS * DD / 8;
    prep_bf16<<<(n8 + 255) / 256, 256, 0, stream>>>(xk, kbf, n8);
    prep_vT<<<NB * HH * (SS / 64), 256, 0, stream>>>(xv, vT);

    hca_fused<<<512, 512, 0, stream>>>(xq, kbf, vT, Wm, causal, out);
}

// Round 3
// 161.845 us; speedup vs baseline: 2.0652x; 1.1610x over previous
//
#include <hip/hip_runtime.h>
#include <math.h>

#define NB 4
#define HH 16
#define SS 1024
#define DD 64

typedef __attribute__((ext_vector_type(8))) short bf16x8;
typedef __attribute__((ext_vector_type(4))) float f32x4;

static __device__ __forceinline__ short f2bf(float f) {
    __bf16 h = (__bf16)f;                       // v_cvt_pk_bf16_f32 (RNE), 1 op
    return __builtin_bit_cast(short, h);
}
static __device__ __forceinline__ float bflo(int w) {
    return __builtin_bit_cast(float, (unsigned)w << 16);
}
static __device__ __forceinline__ float bfhi(int w) {
    return __builtin_bit_cast(float, (unsigned)w & 0xffff0000u);
}
// P LDS [pos=q*64+k][16h as 8 u32-pairs], 3-bit XOR swizzle.
// writer (phase1): 2-way (free); reader (phase1.5, 4x b32): conflict-free.
static __device__ __forceinline__ int pidx(int pos, int hw) {
    int s = ((pos >> 2) & 3) | (((pos >> 8) & 1) << 2);
    return pos * 8 + (hw ^ s);
}
// mixed LDS [16 g][512 pos-pairs u32], XOR swizzle on 4-unit groups.
// writer (b64): at min; reader (b128): uniform 8 lanes/bank-group (min).
static __device__ __forceinline__ int midx(int g, int pp) {
    return g * 512 + (pp ^ ((((pp >> 5) + g) & 7) << 2));
}

static __device__ __forceinline__ bf16x8 load8_bf16(const float* p) {
    const float4* p4 = reinterpret_cast<const float4*>(p);
    float4 a = p4[0], b = p4[1];
    bf16x8 f;
    f[0]=f2bf(a.x); f[1]=f2bf(a.y); f[2]=f2bf(a.z); f[3]=f2bf(a.w);
    f[4]=f2bf(b.x); f[5]=f2bf(b.y); f[6]=f2bf(b.z); f[7]=f2bf(b.w);
    return f;
}

// ---------- prep: f32 -> bf16 copy (K) ----------
__global__ __launch_bounds__(256) void prep_bf16(const float* __restrict__ x,
                                                 short* __restrict__ y, int n8) {
    int i = blockIdx.x * 256 + threadIdx.x;
    if (i >= n8) return;
    *(reinterpret_cast<bf16x8*>(y) + i) = load8_bf16(x + (size_t)i * 8);
}

// ---------- prep: V [B,H,S,D] f32 -> V^T [B,H,D,S] bf16 ----------
__global__ __launch_bounds__(256) void prep_vT(const float* __restrict__ xv,
                                               short* __restrict__ vT) {
    __shared__ float T[64][65];
    int bid = blockIdx.x;            // (b*H+h)*16 + s-tile
    int bh = bid >> 4, st = bid & 15;
    const float* src = xv + ((size_t)bh * SS + st * 64) * DD;
    int t = threadIdx.x;
#pragma unroll
    for (int r = 0; r < 4; ++r) {
        int s = r * 16 + (t >> 4), d = (t & 15) * 4;
        float4 v = *reinterpret_cast<const float4*>(src + s * DD + d);
        T[s][d] = v.x; T[s][d+1] = v.y; T[s][d+2] = v.z; T[s][d+3] = v.w;
    }
    __syncthreads();
#pragma unroll
    for (int r = 0; r < 4; ++r) {
        int d = r * 16 + (t >> 4), s0 = (t & 15) * 4;
        ushort4 o;
        o.x = (ushort)f2bf(T[s0][d]);   o.y = (ushort)f2bf(T[s0+1][d]);
        o.z = (ushort)f2bf(T[s0+2][d]); o.w = (ushort)f2bf(T[s0+3][d]);
        *reinterpret_cast<ushort4*>(vT + ((size_t)bh * DD + d) * SS + st * 64 + s0) = o;
    }
}

// One block = (b, 16-row q-tile), 16 waves, all 16 heads. 3 phases per k-step:
//  1) wave w: QK^T scores for heads {2(w&7), 2(w&7)+1}, kt-half w>>3 -> P (LDS)
//  2) mix across heads via zero-padded 16x16x32 MFMA (K=16 used) -> mixed (LDS)
//  3) wave w: online softmax + PV for output head g=w (log2 domain, defer-rescale)
__global__ __launch_bounds__(1024, 4) void hca_fused(
    const float* __restrict__ xq, const short* __restrict__ kbf,
    const short* __restrict__ vT, const float* __restrict__ Wm,
    const int* __restrict__ causalp, float* __restrict__ out)
{
    __shared__ int4 PbufV[2048];   // 32 KB: P bf16 [1024 pos][16 h]
    __shared__ int4 MbufV[2048];   // 32 KB: mixed bf16 [16 g][1024 pos]
    int* Pbuf = reinterpret_cast<int*>(PbufV);
    int* Mbuf = reinterpret_cast<int*>(MbufV);

    const int tid  = threadIdx.x;
    const int lane = tid & 63;
    const int w    = tid >> 6;     // wave 0..15
    const int l15  = lane & 15;
    const int lg   = lane >> 4;    // 0..3

    const int bid = blockIdx.x;
    const int b   = bid & 3;       // same b per XCD -> K/V L2-resident
    const int qt  = bid >> 2;
    const int q0  = qt << 4;

    const int causal = causalp[0];
    const int hp = w & 7;          // phase-1 head pair (heads 2hp, 2hp+1)
    const int kh = w >> 3;         // phase-1 kt half
    const int g  = w;              // phase-3 output head

    const float LOG2E = 1.44269504088896f;

    // W fragment for the mix MFMA: B[k=h][n=g], lanes lg<2 hold h=lg*8+i.
    bf16x8 wt = {0,0,0,0,0,0,0,0};
    if (lg < 2) {
#pragma unroll
        for (int i = 0; i < 8; ++i)
            wt[i] = f2bf(Wm[l15 * 16 + lg * 8 + i] * 0.125f * LOG2E);
    }

    // Q A-fragments for the phase-1 head pair
    bf16x8 qf[2][2];
#pragma unroll
    for (int hi = 0; hi < 2; ++hi) {
        const float* qp = xq + ((size_t)(b * HH + 2 * hp + hi) * SS + q0 + l15) * DD + lg * 8;
#pragma unroll
        for (int ds = 0; ds < 2; ++ds) qf[hi][ds] = load8_bf16(qp + ds * 32);
    }

    f32x4 oacc[4];
#pragma unroll
    for (int nt = 0; nt < 4; ++nt) oacc[nt] = (f32x4){0.f, 0.f, 0.f, 0.f};
    float mrun = -INFINITY, lrun = 0.f;

    const short* kb0 = kbf + (size_t)(b * HH + 2 * hp) * SS * DD;
    const short* vb  = vT  + (size_t)(b * HH + g) * DD * SS;

    const int nk = causal ? ((q0 + 16 + 63) >> 6) : (SS >> 6);

    for (int kst = 0; kst < nk; ++kst) {
        const int k0 = kst << 6;

        // ---------- phase 1: scores for 2 heads x 16q x 32k ----------
#pragma unroll
        for (int kt2 = 0; kt2 < 2; ++kt2) {
            const int kt = kh * 2 + kt2;
            const short* kra = kb0 + (size_t)(k0 + kt * 16 + l15) * DD + lg * 8;
            f32x4 a0 = (f32x4){0.f,0.f,0.f,0.f}, a1 = a0;
#pragma unroll
            for (int ds = 0; ds < 2; ++ds) {
                bf16x8 kfa = *reinterpret_cast<const bf16x8*>(kra + ds * 32);
                bf16x8 kfb = *reinterpret_cast<const bf16x8*>(kra + (size_t)SS * DD + ds * 32);
                a0 = __builtin_amdgcn_mfma_f32_16x16x32_bf16(qf[0][ds], kfa, a0, 0, 0, 0);
                a1 = __builtin_amdgcn_mfma_f32_16x16x32_bf16(qf[1][ds], kfb, a1, 0, 0, 0);
            }
#pragma unroll
            for (int r = 0; r < 4; ++r) {
                int pos = (lg * 4 + r) * 64 + kt * 16 + l15;
                int pk = (int)(unsigned short)f2bf(a0[r]) | ((int)(unsigned short)f2bf(a1[r]) << 16);
                Pbuf[pidx(pos, hp)] = pk;
            }
        }
        __syncthreads();

        // ---------- phase 1.5: head mix via MFMA (K=16, zero-padded) ----------
#pragma unroll
        for (int m = 0; m < 4; ++m) {
            const int c = w * 4 + m;           // 16-pos chunk
            const int pos = c * 16 + l15;
            int4 ia = {0, 0, 0, 0};
            if (lg < 2) {
                ia.x = Pbuf[pidx(pos, lg * 4 + 0)];
                ia.y = Pbuf[pidx(pos, lg * 4 + 1)];
                ia.z = Pbuf[pidx(pos, lg * 4 + 2)];
                ia.w = Pbuf[pidx(pos, lg * 4 + 3)];
            }
            bf16x8 A = __builtin_bit_cast(bf16x8, ia);
            f32x4 cc = (f32x4){0.f, 0.f, 0.f, 0.f};
            cc = __builtin_amdgcn_mfma_f32_16x16x32_bf16(A, wt, cc, 0, 0, 0);
            // lane: g=l15, pos = c*16 + lg*4 + r -> two u32 (pos-pairs), one b64
            int u0 = (int)(unsigned short)f2bf(cc[0]) | ((int)(unsigned short)f2bf(cc[1]) << 16);
            int u1 = (int)(unsigned short)f2bf(cc[2]) | ((int)(unsigned short)f2bf(cc[3]) << 16);
            *reinterpret_cast<int2*>(&Mbuf[midx(l15, c * 8 + lg * 2)]) = make_int2(u0, u1);
        }

        // issue V loads early: independent of LDS, latency hides under barrier+softmax
        bf16x8 vf[8];
#pragma unroll
        for (int kc = 0; kc < 2; ++kc)
#pragma unroll
            for (int nt = 0; nt < 4; ++nt)
                vf[kc * 4 + nt] = *reinterpret_cast<const bf16x8*>(
                    vb + (size_t)(nt * 16 + l15) * SS + k0 + kc * 32 + lg * 8);
        __syncthreads();

        // ---------- phase 2: softmax (log2 domain) + PV for head g ----------
        const int base0 = l15 * 32 + lg * 4;
        const int xsw = ((l15 + g) & 7) << 2;
        int4 rA = *reinterpret_cast<const int4*>(&Mbuf[g * 512 + (base0 ^ xsw)]);
        int4 rB = *reinterpret_cast<const int4*>(&Mbuf[g * 512 + ((base0 + 16) ^ xsw)]);

        float sm[16];
#pragma unroll
        for (int jj = 0; jj < 4; ++jj) {
            sm[2*jj]     = bflo(rA[jj]);  sm[2*jj + 1]  = bfhi(rA[jj]);
            sm[8 + 2*jj] = bflo(rB[jj]);  sm[9 + 2*jj]  = bfhi(rB[jj]);
        }
        if (causal && kst == nk - 1) {
#pragma unroll
            for (int j = 0; j < 16; ++j) {
                int kk = (j < 8) ? (lg * 8 + j) : (32 + lg * 8 + (j - 8));
                if (k0 + kk > q0 + l15) sm[j] = -INFINITY;
            }
        }

        float m01 = fmaxf(sm[0], sm[1]),  m23 = fmaxf(sm[2], sm[3]);
        float m45 = fmaxf(sm[4], sm[5]),  m67 = fmaxf(sm[6], sm[7]);
        float m89 = fmaxf(sm[8], sm[9]),  mab = fmaxf(sm[10], sm[11]);
        float mcd = fmaxf(sm[12], sm[13]), mef = fmaxf(sm[14], sm[15]);
        float mt = fmaxf(fmaxf(fmaxf(m01, m23), fmaxf(m45, m67)),
                         fmaxf(fmaxf(m89, mab), fmaxf(mcd, mef)));
        mt = fmaxf(mt, __shfl_xor(mt, 16));
        mt = fmaxf(mt, __shfl_xor(mt, 32));

        if (__any(mt > mrun + 8.0f)) {            // defer-rescale (T13)
            float mnew = fmaxf(mrun, mt);
            float scl = __builtin_amdgcn_exp2f(mrun - mnew);
            mrun = mnew;
            lrun *= scl;
            int scli = __builtin_bit_cast(int, scl);
#pragma unroll
            for (int r = 0; r < 4; ++r) {
                int v = __builtin_amdgcn_ds_bpermute((lg * 4 + r) * 4, scli);
                float s = __builtin_bit_cast(float, v);
#pragma unroll
                for (int nt = 0; nt < 4; ++nt) oacc[nt][r] *= s;
            }
        }

        float p[16];
#pragma unroll
        for (int j = 0; j < 16; ++j) p[j] = __builtin_amdgcn_exp2f(sm[j] - mrun);
        float s0 = ((p[0]+p[1]) + (p[2]+p[3])) + ((p[4]+p[5]) + (p[6]+p[7]));
        float s1 = ((p[8]+p[9]) + (p[10]+p[11])) + ((p[12]+p[13]) + (p[14]+p[15]));
        lrun += s0 + s1;

        int paw[8];
#pragma unroll
        for (int t = 0; t < 8; ++t)
            paw[t] = (int)(unsigned short)f2bf(p[2*t]) | ((int)(unsigned short)f2bf(p[2*t+1]) << 16);
        bf16x8 pa0 = __builtin_bit_cast(bf16x8, *(int4*)&paw[0]);
        bf16x8 pa1 = __builtin_bit_cast(bf16x8, *(int4*)&paw[4]);

#pragma unroll
        for (int nt = 0; nt < 4; ++nt) {
            oacc[nt] = __builtin_amdgcn_mfma_f32_16x16x32_bf16(pa0, vf[nt], oacc[nt], 0, 0, 0);
            oacc[nt] = __builtin_amdgcn_mfma_f32_16x16x32_bf16(pa1, vf[4 + nt], oacc[nt], 0, 0, 0);
        }
        __syncthreads();   // protect P/mixed for next step
    }

    // ---------- epilogue ----------
    float lt = lrun;
    lt += __shfl_xor(lt, 16);
    lt += __shfl_xor(lt, 32);
    int lti = __builtin_bit_cast(int, lt);
#pragma unroll
    for (int r = 0; r < 4; ++r) {
        int v = __builtin_amdgcn_ds_bpermute((lg * 4 + r) * 4, lti);
        float linv = 1.0f / __builtin_bit_cast(float, v);
        int q = lg * 4 + r;
#pragma unroll
        for (int nt = 0; nt < 4; ++nt)
            out[((size_t)(b * SS + q0 + q) * HH + g) * DD + nt * 16 + l15] =
                oacc[nt][r] * linv;
    }
}

extern "C" void kernel_launch(void* const* d_in, const int* in_sizes, int n_in,
                              void* d_out, int out_size, void* d_ws, size_t ws_size,
                              hipStream_t stream) {
    const float* xq = (const float*)d_in[0];
    const float* xk = (const float*)d_in[1];
    const float* xv = (const float*)d_in[2];
    const float* Wm = (const float*)d_in[3];
    const int* causal = (const int*)d_in[4];
    float* out = (float*)d_out;

    short* vT  = (short*)d_ws;                       // 8 MB bf16 V^T
    short* kbf = vT + (size_t)NB * HH * DD * SS;     // 8 MB bf16 K

    const int n8 = NB * HH * SS * DD / 8;
    prep_bf16<<<(n8 + 255) / 256, 256, 0, stream>>>(xk, kbf, n8);
    prep_vT<<<NB * HH * (SS / 64), 256, 0, stream>>>(xv, vT);

    hca_fused<<<NB * (SS / 16), 1024, 0, stream>>>(xq, kbf, vT, Wm, causal, out);
}